// Round 11
// baseline (18.023 us; speedup 1.0000x reference)
//
#include <hip/hip_runtime.h>

// Problem constants (fixed by the bench: B=8, L=512, T=4096, D=512).
constexpr int B = 8;
constexpr int L = 512;
constexpr int D = 512;
constexpr int T = 4096;

constexpr int OUT_REP = B * D * T;        // offset of repeats in d_out
constexpr int OUT_LAT = OUT_REP + B * L;  // offset of latent_lengths

// R11 = R10 + XCD-aware block swizzle (single change).
// R10 proved DRAM-level store sequentiality is the lever (32 KB contiguous
// span per block: 20.45 -> 17.68 us). With linear bid, adjacent spans are
// dispatched round-robin to different XCDs, so each per-XCD L2 sees a
// 32 KB-grain strided write stream. The bijective swizzle (2048 % 8 == 0)
// gives each XCD one contiguous ~8.4 MB region => sequential per-L2 streams.
__global__ __launch_bounds__(256) void encoder_expand_kernel(
    const float* __restrict__ enc,   // (B, D, L)
    const float* __restrict__ dur,   // (B, L)
    float* __restrict__ out)         // [expanded (B,D,T) | repeats (B,L) | latent (B)]
{
    // XCD-aware swizzle: wg i runs on XCD i%8 (round-robin dispatch);
    // give XCD k the contiguous block range [k*256, (k+1)*256).
    const int bid = (blockIdx.x & 7) * 256 + (blockIdx.x >> 3);
    const int b   = bid >> 8;               // 0..7
    const int rp  = bid & 255;              // row pair 0..255 (d = 2*rp, 2*rp+1)
    const int tid = threadIdx.x;
    const int lane = tid & 63;
    const int wave = tid >> 6;              // 0..3

    __shared__ unsigned short lut[T];       // 8 KB  t -> l, 0xFFFF = past end
    __shared__ float rows[2 * L];           // 4 KB  staged enc rows
    __shared__ int wave_tot[4];

    // ---- issue global loads first (independent) ----
    const float2 dur2 = *reinterpret_cast<const float2*>(dur + b * L + 2 * tid);
    const float* encp = enc + ((size_t)b * D + 2 * rp) * L;   // 2 rows, contiguous
    const float4 rv = reinterpret_cast<const float4*>(encp)[tid];  // 4 KB coalesced

    // ---- init LUT sentinel (2048 u32) while loads are in flight ----
    #pragma unroll
    for (int i = 0; i < T / 2 / 256; ++i)
        reinterpret_cast<unsigned*>(lut)[i * 256 + tid] = 0xFFFFFFFFu;

    // ---- stage enc rows ----
    reinterpret_cast<float4*>(rows)[tid] = rv;

    // ---- repeats + scan over L=512 (2 elems/thread) ----
    const int r0 = (int)floorf(dur2.x + 0.5f);
    const int r1 = (int)floorf(dur2.y + 0.5f);
    const int pair = r0 + r1;

    int scan = pair;                        // wave-level inclusive scan
    #pragma unroll
    for (int off = 1; off < 64; off <<= 1) {
        int n = __shfl_up(scan, off, 64);
        if (lane >= off) scan += n;
    }
    if (lane == 63) wave_tot[wave] = scan;
    __syncthreads();                        // lut init + rows + wave_tot visible

    int wpre = 0;
    #pragma unroll
    for (int w = 0; w < 4; ++w) wpre += (w < wave) ? wave_tot[w] : 0;
    int k = wpre + scan - pair;             // exclusive prefix = t-start of l0's span
    const int total = wave_tot[0] + wave_tot[1] + wave_tot[2] + wave_tot[3];

    // ---- scatter: each l writes its own span (disjoint ranges, no race) ----
    const int l0 = 2 * tid;
    for (int q = 0; q < r0; ++q, ++k) if (k < T) lut[k] = (unsigned short)l0;
    for (int q = 0; q < r1; ++q, ++k) if (k < T) lut[k] = (unsigned short)(l0 + 1);

    // ---- side outputs (one block per batch) ----
    if (rp == 0) {
        out[OUT_REP + b * L + l0]     = (float)r0;
        out[OUT_REP + b * L + l0 + 1] = (float)r1;
        if (tid == 0) out[OUT_LAT + b] = (float)total;
    }
    __syncthreads();                        // scatter done

    // ---- payload: 8 sequential block-wide 4 KB sweeps over the 32 KB span ----
    float4* out4 = reinterpret_cast<float4*>(out + ((size_t)b * D + 2 * rp) * T);

    #pragma unroll
    for (int s = 0; s < 8; ++s) {
        const int row = s >> 2;             // 0..1
        const int seg = s & 3;              // 0..3 (1024-t segment)
        const int t0  = seg * 1024 + 4 * tid;

        float4 v = make_float4(0.f, 0.f, 0.f, 0.f);
        if (seg * 1024 < total) {           // block-uniform zero-skip
            const uint2 lu = *reinterpret_cast<const uint2*>(&lut[t0]);
            const int la = lu.x & 0xffff, lb = lu.x >> 16;
            const int lc = lu.y & 0xffff, ld = lu.y >> 16;
            const float* rowp = rows + row * L;
            v.x = rowp[la & 511];           // monotone l across lanes: ~2-way banks (free)
            v.y = rowp[lb & 511];
            v.z = rowp[lc & 511];
            v.w = rowp[ld & 511];
            if (la == 0xffff) v.x = 0.0f;
            if (lb == 0xffff) v.y = 0.0f;
            if (lc == 0xffff) v.z = 0.0f;
            if (ld == 0xffff) v.w = 0.0f;
        }
        out4[(row * 4 + seg) * 256 + tid] = v;   // block-wide 4 KB sequential store
    }
}

extern "C" void kernel_launch(void* const* d_in, const int* in_sizes, int n_in,
                              void* d_out, int out_size, void* d_ws, size_t ws_size,
                              hipStream_t stream) {
    const float* enc = (const float*)d_in[0];   // (B, D, L) fp32
    const float* dur = (const float*)d_in[1];   // (B, L)    fp32
    float* out = (float*)d_out;
    encoder_expand_kernel<<<dim3(B * (D / 2)), dim3(256), 0, stream>>>(enc, dur, out);
}